// Round 1
// baseline (305.192 us; speedup 1.0000x reference)
//
#include <hip/hip_runtime.h>

// out[b,m,c] = sum_{k<3} vals[m,k] * x[b, cols[m,k], c]
// B=8, N=50000, C=128, M=25000, K=3, all fp32.
// One thread per (b, m, c4) where c4 indexes a float4 (C/4 = 32 quads).
// Flat tid t = ((b*M + m)*32 + c4) makes the output store exactly
// ((float4*)out)[t] -> perfectly coalesced; each 32-lane group reads one
// contiguous 512B row of x per gather index.

#define B_ 8
#define N_ 50000
#define C_ 128
#define M_ 25000

__global__ __launch_bounds__(256) void mesh_gather_kernel(
    const float* __restrict__ x,      // [B, N, C]
    const int* __restrict__ cols,     // [M, 3]
    const float* __restrict__ vals,   // [M, 3]
    float* __restrict__ out)          // [B, M, C]
{
    int t = blockIdx.x * blockDim.x + threadIdx.x;       // < B*M*32 = 6.4M
    const int total = B_ * M_ * (C_ / 4);
    if (t >= total) return;

    int c4 = t & 31;                 // 0..31 (float4 index within row)
    int m  = (t >> 5) % M_;
    int b  = t / (M_ * 32);

    int i0 = cols[m * 3 + 0];
    int i1 = cols[m * 3 + 1];
    int i2 = cols[m * 3 + 2];
    float v0 = vals[m * 3 + 0];
    float v1 = vals[m * 3 + 1];
    float v2 = vals[m * 3 + 2];

    const float4* xb = (const float4*)(x + (long long)b * N_ * C_);
    float4 a = xb[(long long)i0 * 32 + c4];
    float4 bq = xb[(long long)i1 * 32 + c4];
    float4 cq = xb[(long long)i2 * 32 + c4];

    float4 r;
    r.x = v0 * a.x + v1 * bq.x + v2 * cq.x;
    r.y = v0 * a.y + v1 * bq.y + v2 * cq.y;
    r.z = v0 * a.z + v1 * bq.z + v2 * cq.z;
    r.w = v0 * a.w + v1 * bq.w + v2 * cq.w;

    ((float4*)out)[t] = r;
}

extern "C" void kernel_launch(void* const* d_in, const int* in_sizes, int n_in,
                              void* d_out, int out_size, void* d_ws, size_t ws_size,
                              hipStream_t stream) {
    const float* x    = (const float*)d_in[0];
    const int*   cols = (const int*)d_in[1];
    const float* vals = (const float*)d_in[2];
    float* out = (float*)d_out;

    const int total = B_ * M_ * (C_ / 4);   // 6,400,000
    const int block = 256;
    const int grid = (total + block - 1) / block;  // 25000
    mesh_gather_kernel<<<grid, block, 0, stream>>>(x, cols, vals, out);
}